// Round 2
// baseline (249.968 us; speedup 1.0000x reference)
//
#include <hip/hip_runtime.h>

// R9: (1) attn: grid was only 2 blocks/CU (grid-limited!) -> q-tile 64,
// grid (32,32) = 4 blocks/CU, 256-thread 2x2 wave split (R7's proven
// register shape, no spills). V LDS staging dropped: V frags read direct
// from L2 (swizzle algebra cancels; address verified). LDS 33.3 KB.
// (2) X pre-converted to bf16 once (xcvt kernel, also computes masks) --
// kills the 4x-redundant fp32 fetch+convert in proj; proj becomes a pure
// bf16 double-buffered single-barrier-per-K-step GEMM with XOR-swizzled
// A AND B staging (old 64B-row frag reads were 2x min bank cycles).
// Xb_q/Xb_k staged in d_out (dead until attn), Xb_v in ws.

typedef __attribute__((ext_vector_type(8))) __bf16 bf16x8;
typedef __attribute__((ext_vector_type(4))) float f32x4;

#if __has_builtin(__builtin_amdgcn_exp2f)
#define EXP2F __builtin_amdgcn_exp2f
#else
#define EXP2F exp2f
#endif

#define QSCALE (0.125f * 1.4426950408889634f)  // fold /sqrt(64) and ln->log2

__device__ __forceinline__ unsigned short f2bf(float f) {
  return __builtin_bit_cast(unsigned short, (__bf16)f);
}
__device__ __forceinline__ unsigned pk2(float a, float b) {
  return (unsigned)f2bf(a) | ((unsigned)f2bf(b) << 16);
}
__device__ __forceinline__ f32x4 mfma16(bf16x8 a, bf16x8 b, f32x4 c) {
  return __builtin_amdgcn_mfma_f32_16x16x32_bf16(a, b, c, 0, 0, 0);
}
__device__ __forceinline__ bf16x8 ld_bf8(const unsigned short* p) {
  return *(const bf16x8*)p;
}
// async global->LDS, 16 B per lane; LDS dst is wave-uniform base + lane*16
__device__ __forceinline__ void g2l16(const void* g, void* l) {
  __builtin_amdgcn_global_load_lds(
      (const __attribute__((address_space(1))) void*)g,
      (__attribute__((address_space(3))) void*)l, 16, 0, 0);
}

// ---------------------------------------------------------------------------
// Kernel 1: transpose + convert the three 512x512 weight matrices to bf16,
// layout Wt[z][n][k] (n-major) so MFMA B-fragments read contiguous k.
// ---------------------------------------------------------------------------
__global__ __launch_bounds__(256) void wt_kernel(const float* __restrict__ Wq,
                                                 const float* __restrict__ Wk,
                                                 const float* __restrict__ Wv,
                                                 unsigned short* __restrict__ Wt) {
  int idx = blockIdx.x * 256 + threadIdx.x;
  int o = idx * 8;
  int z = o >> 18;
  int rem = o & 262143;
  int n = rem >> 9;
  int k0 = rem & 511;
  const float* W = (z == 0) ? Wq : ((z == 1) ? Wk : Wv);
  unsigned int w[4];
#pragma unroll
  for (int i = 0; i < 4; ++i) {
    unsigned short lo = f2bf(W[(k0 + 2 * i) * 512 + n]);
    unsigned short hi = f2bf(W[(k0 + 2 * i + 1) * 512 + n]);
    w[i] = (unsigned)lo | ((unsigned)hi << 16);
  }
  *(uint4*)(Wt + o) = make_uint4(w[0], w[1], w[2], w[3]);
}

// ---------------------------------------------------------------------------
// Kernel 1b: convert X (queries/keys/values) fp32->bf16 rows, and compute
// the padding masks from exact fp32 row sums: qmask (0/1, multiplicative)
// and kbias (0/-1e30, folded into the QK MFMA accumulator init).
// One wave per 512-float row; 6144 blocks x 4 rows.
// ---------------------------------------------------------------------------
__global__ __launch_bounds__(256) void xcvt_kernel(
    const float* __restrict__ Xq, const float* __restrict__ Xk,
    const float* __restrict__ Xv, unsigned short* __restrict__ Xbq,
    unsigned short* __restrict__ Xbk, unsigned short* __restrict__ Xbv,
    float* __restrict__ qmask, float* __restrict__ kbias) {
  int row = blockIdx.x * 4 + (threadIdx.x >> 6);
  int lane = threadIdx.x & 63;
  int z = row >> 13;
  int r = row & 8191;
  const float* X = (z == 0) ? Xq : ((z == 1) ? Xk : Xv);
  unsigned short* Xb = (z == 0) ? Xbq : ((z == 1) ? Xbk : Xbv);
  const float* p = X + r * 512 + lane * 8;
  f32x4 lo = *(const f32x4*)p;
  f32x4 hi = *(const f32x4*)(p + 4);
  *(uint4*)(Xb + r * 512 + lane * 8) =
      make_uint4(pk2(lo[0], lo[1]), pk2(lo[2], lo[3]), pk2(hi[0], hi[1]),
                 pk2(hi[2], hi[3]));
  if (z < 2) {
    float s = lo[0] + lo[1] + lo[2] + lo[3] + hi[0] + hi[1] + hi[2] + hi[3];
#pragma unroll
    for (int off = 1; off < 64; off <<= 1) s += __shfl_xor(s, off);
    if (lane == 0) {
      if (z == 0)
        qmask[r] = (s == 0.f) ? 0.f : 1.f;
      else
        kbias[r] = (s == 0.f) ? -1.0e30f : 0.f;
    }
  }
}

// ---------------------------------------------------------------------------
// Kernel 2: QKV projection, pure-bf16 double-buffered GEMM, ONE barrier per
// K-step (stage next tile -> read frags -> MFMA -> syncthreads). A and B
// staged [128][32] shorts with source-side XOR swizzle slot^((row>>1)&3)
// (16B slots) so fragment reads hit the minimum bank cycles.
// Grid (192 m-blocks, 4 n-blocks); z = m-block/64. Tile 128x128, BK=32.
// V stored transposed with the permuted intra-32-key order
// (pos = quad*8 + sub*4 + r), matching attn's P register-repack k-order.
// ---------------------------------------------------------------------------
__global__ __launch_bounds__(256, 4) void proj_kernel(
    const unsigned short* __restrict__ Xbq, const unsigned short* __restrict__ Xbk,
    const unsigned short* __restrict__ Xbv, const float* __restrict__ bq,
    const float* __restrict__ bk, const float* __restrict__ bv,
    const unsigned short* __restrict__ Wt, unsigned short* __restrict__ Qb,
    unsigned short* __restrict__ Kb, unsigned short* __restrict__ Vt) {
  __shared__ unsigned short Asm[2][128][32];
  __shared__ unsigned short Bsm[2][128][32];

  int tid = threadIdx.x;
  int m0g = blockIdx.x * 128;
  int z = m0g >> 13;
  int m0 = m0g & 8191;
  int n0 = blockIdx.y * 128;
  const unsigned short* Xb = (z == 0) ? Xbq : ((z == 1) ? Xbk : Xbv);
  const float* bias = (z == 0) ? bq : ((z == 1) ? bk : bv);
  const unsigned short* Wz = Wt + z * 262144;

  int w = tid >> 6, lane = tid & 63;
  int wm = w >> 1, wn = w & 1;
  int mrow = lane & 15, quad = lane >> 4;

  // staging: row = tid>>2 (0..63; +64 in 2nd call), slot = tid&3 (16B),
  // source slot XOR-swizzled by (row>>1)&3; LDS stays linear (g2l16).
  int srow = tid >> 2, sslot = tid & 3;
  int sxs = sslot ^ ((srow >> 1) & 3);
  const unsigned short* gA = Xb + (m0 + srow) * 512 + sxs * 8;
  const unsigned short* gB = Wz + (n0 + srow) * 512 + sxs * 8;
  char* lA = (char*)&Asm[0][0][0] + tid * 16;
  char* lB = (char*)&Bsm[0][0][0] + tid * 16;

  // fragment read slot (un-swizzles; (row>>1)&3 == (mrow>>1)&3 here)
  int rs = (quad ^ ((mrow >> 1) & 3)) * 8;

  f32x4 zero = {0.f, 0.f, 0.f, 0.f};
  f32x4 acc[4][4];
#pragma unroll
  for (int i = 0; i < 4; ++i)
#pragma unroll
    for (int j = 0; j < 4; ++j) acc[i][j] = zero;

  // prologue: stage kc=0 into buf 0
  g2l16(gA, lA);
  g2l16(gA + 64 * 512, lA + 4096);
  g2l16(gB, lB);
  g2l16(gB + 64 * 512, lB + 4096);
  __syncthreads();

  for (int kc = 0; kc < 16; ++kc) {
    int cur = kc & 1;
    if (kc < 15) {
      int ko = (kc + 1) * 32;
      int nb = cur ^ 1;
      g2l16(gA + ko, lA + nb * 8192);
      g2l16(gA + ko + 64 * 512, lA + nb * 8192 + 4096);
      g2l16(gB + ko, lB + nb * 8192);
      g2l16(gB + ko + 64 * 512, lB + nb * 8192 + 4096);
    }
    bf16x8 af[4], bfr[4];
#pragma unroll
    for (int mt = 0; mt < 4; ++mt)
      af[mt] = ld_bf8(&Asm[cur][wm * 64 + mt * 16 + mrow][rs]);
#pragma unroll
    for (int nt = 0; nt < 4; ++nt)
      bfr[nt] = ld_bf8(&Bsm[cur][wn * 64 + nt * 16 + mrow][rs]);
#pragma unroll
    for (int mt = 0; mt < 4; ++mt)
#pragma unroll
      for (int nt = 0; nt < 4; ++nt)
        acc[mt][nt] = mfma16(af[mt], bfr[nt], acc[mt][nt]);
    __syncthreads();
  }

  if (z < 2) {
    unsigned short* dst = (z == 0) ? Qb : Kb;
    float sc = (z == 0) ? QSCALE : 1.0f;
#pragma unroll
    for (int nt = 0; nt < 4; ++nt) {
      int n = n0 + wn * 64 + nt * 16 + mrow;
      float bv_ = bias[n];
#pragma unroll
      for (int mt = 0; mt < 4; ++mt) {
        int m = m0 + wm * 64 + mt * 16 + quad * 4;
#pragma unroll
        for (int r = 0; r < 4; ++r) {
          float v = fmaxf(acc[mt][nt][r] + bv_, 0.f) * sc;
          dst[(m + r) * 512 + n] = f2bf(v);
        }
      }
    }
  } else {
    // V: permuted-transposed store (pos = quad*8 + (mt&1)*4 + r in 32-t group)
#pragma unroll
    for (int nt = 0; nt < 4; ++nt) {
      int n = n0 + wn * 64 + nt * 16 + mrow;
      int hh = n >> 6, jj = n & 63;
      float bv_ = bias[n];
#pragma unroll
      for (int mt = 0; mt < 4; ++mt) {
        int grow = m0 + wm * 64 + mt * 16 + quad * 4;
        int bb = grow >> 11, tl = grow & 2047;
        int pos = (tl & ~31) + quad * 8 + (mt & 1) * 4;
        float p0 = fmaxf(acc[mt][nt][0] + bv_, 0.f);
        float p1 = fmaxf(acc[mt][nt][1] + bv_, 0.f);
        float p2 = fmaxf(acc[mt][nt][2] + bv_, 0.f);
        float p3 = fmaxf(acc[mt][nt][3] + bv_, 0.f);
        *(uint2*)(Vt + ((hh * 4 + bb) * 64 + jj) * 2048 + pos) =
            make_uint2(pk2(p0, p1), pk2(p2, p3));
      }
    }
  }
}

// ---------------------------------------------------------------------------
// Kernel 3: attention. Grid (hb=32, qt=32); block = 64 q, 256 threads,
// 4 waves in 2x2: qh = wave>>1 owns 32 queries, kh2 = wave&1 owns the 64-key
// half of each 128-key chunk. 1024 blocks = 4 blocks/CU (16 waves/CU).
// 16 chunks, ONE barrier per chunk, double-buffered K LDS (2 x 16 KB) via
// g2l16 with XOR swizzle. V frags read DIRECT from global (L2-resident;
// staged-address algebra cancels to kb + (kh2*8+kg*4+quad)*8).
// QK: S^T = K*Q^T seeded with kbias (mask pre-folded). PV: O = P*V^T with
// P as A-operand (register repack, Vt permuted to match). Epilogue:
// cross-wave (kh2) O/l combine through LDS aliased onto the staging buffer.
// ---------------------------------------------------------------------------
__global__ __launch_bounds__(256, 4) void attn_kernel(
    const unsigned short* __restrict__ Qb, const unsigned short* __restrict__ Kb,
    const unsigned short* __restrict__ Vt, const float* __restrict__ qmask,
    const float* __restrict__ kbias, const float* __restrict__ queries,
    float* __restrict__ out) {
  __shared__ char smem[33280];
  unsigned short* KsmS = (unsigned short*)smem;  // [2][8192] shorts
  float* Obuf = (float*)smem;                    // [64][65] floats alias
  float* lbuf = (float*)(smem + 32768);          // [2][64]

  int hb = blockIdx.x;
  int qt = blockIdx.y;
  int h = hb >> 2, b = hb & 3;
  int q0 = qt * 64;
  int tid = threadIdx.x;
  int w = tid >> 6, lane = tid & 63;
  int qh = w >> 1, kh2 = w & 1;
  int mrow = lane & 15, quad = lane >> 4;
  int mlow = mrow & 7;

  // K staging source (XOR-swizzled slot->chunk), 16 KB per 128-key chunk
  const unsigned short* gK =
      Kb + (b * 2048 + (tid >> 3)) * 512 + h * 64 + (((tid & 7) ^ ((tid >> 3) & 7)) * 8);
  // V direct-from-global fragment base (row = dh, permuted col slot)
  const unsigned short* gV =
      Vt + (hb * 64 + mrow) * 2048 + (kh2 * 8 + quad) * 8;

  // Q B-frags [n=q qn*16+mrow][k=dh quad*8 (+32)]
  bf16x8 qf[2][2];
  {
    const unsigned short* qp =
        Qb + (b * 2048 + q0 + qh * 32 + mrow) * 512 + h * 64 + quad * 8;
#pragma unroll
    for (int qn = 0; qn < 2; ++qn) {
      qf[qn][0] = ld_bf8(qp + qn * 8192);
      qf[qn][1] = ld_bf8(qp + qn * 8192 + 32);
    }
  }

  f32x4 zero = {0.f, 0.f, 0.f, 0.f};
  f32x4 oacc[4][2];  // [dt][qn]: col=dh dt*16+mrow, row=q quad*4+r
#pragma unroll
  for (int i = 0; i < 4; ++i)
#pragma unroll
    for (int j = 0; j < 2; ++j) oacc[i][j] = zero;
  float lpart[2] = {0.f, 0.f};

  const float* kmB = kbias + b * 2048 + kh2 * 64 + quad * 4;
  const int kfrow = kh2 * 64;  // key-row base in Ksm

  // preload chunk 0 into buf 0
#pragma unroll
  for (int j = 0; j < 4; ++j)
    g2l16(gK + j * 32 * 512, &KsmS[j * 2048 + tid * 8]);

  for (int it = 0; it < 16; ++it) {
    int bi = it & 1;
    int kb = it * 128;
    __syncthreads();  // drains staging DMA; buf bi ready

    if (it < 15) {
      int nb = 1 - bi;
#pragma unroll
      for (int j = 0; j < 4; ++j)
        g2l16(gK + (kb + 128 + j * 32) * 512, &KsmS[nb * 8192 + j * 2048 + tid * 8]);
    }

#pragma unroll
    for (int kg = 0; kg < 2; ++kg) {
      f32x4 km0 = *(const f32x4*)(kmB + kb + kg * 32);
      f32x4 km1 = *(const f32x4*)(kmB + kb + kg * 32 + 16);
      bf16x8 kfA0 = ld_bf8(&KsmS[bi * 8192 + (kfrow + kg * 32 + mrow) * 64 +
                                 ((quad) ^ mlow) * 8]);
      bf16x8 kfA1 = ld_bf8(&KsmS[bi * 8192 + (kfrow + kg * 32 + mrow) * 64 +
                                 ((4 + quad) ^ mlow) * 8]);
      bf16x8 kfB0 = ld_bf8(&KsmS[bi * 8192 + (kfrow + kg * 32 + 16 + mrow) * 64 +
                                 ((quad) ^ mlow) * 8]);
      bf16x8 kfB1 = ld_bf8(&KsmS[bi * 8192 + (kfrow + kg * 32 + 16 + mrow) * 64 +
                                 ((4 + quad) ^ mlow) * 8]);
      bf16x8 vfg[4];
#pragma unroll
      for (int dt = 0; dt < 4; ++dt)
        vfg[dt] = ld_bf8(gV + dt * 16 * 2048 + kb + kg * 32);

      f32x4 sA[2], sB[2];
#pragma unroll
      for (int qn = 0; qn < 2; ++qn) {
        f32x4 s0 = mfma16(kfA0, qf[qn][0], km0);
        sA[qn] = mfma16(kfA1, qf[qn][1], s0);
        f32x4 s1 = mfma16(kfB0, qf[qn][0], km1);
        sB[qn] = mfma16(kfB1, qf[qn][1], s1);
      }
#pragma unroll
      for (int qn = 0; qn < 2; ++qn) {
        f32x4 p0, p1;
#pragma unroll
        for (int r = 0; r < 4; ++r) {
          p0[r] = EXP2F(sA[qn][r]);
          p1[r] = EXP2F(sB[qn][r]);
        }
        lpart[qn] += p0[0] + p0[1] + p0[2] + p0[3] + p1[0] + p1[1] + p1[2] + p1[3];
        bf16x8 pf = __builtin_bit_cast(
            bf16x8, make_uint4(pk2(p0[0], p0[1]), pk2(p0[2], p0[3]),
                               pk2(p1[0], p1[1]), pk2(p1[2], p1[3])));
#pragma unroll
        for (int dt = 0; dt < 4; ++dt)
          oacc[dt][qn] = mfma16(pf, vfg[dt], oacc[dt][qn]);
      }
    }
  }

  // --- epilogue: reduce l over quads; combine kh2 halves through LDS
#pragma unroll
  for (int qn = 0; qn < 2; ++qn) {
    lpart[qn] += __shfl_xor(lpart[qn], 16);
    lpart[qn] += __shfl_xor(lpart[qn], 32);
  }
  __syncthreads();  // all staging reads done; smem reusable
  if (quad == 0) {
#pragma unroll
    for (int qn = 0; qn < 2; ++qn)
      lbuf[kh2 * 64 + qh * 32 + qn * 16 + mrow] = lpart[qn];
  }
  if (kh2 == 1) {
#pragma unroll
    for (int dt = 0; dt < 4; ++dt)
#pragma unroll
      for (int qn = 0; qn < 2; ++qn)
#pragma unroll
        for (int r = 0; r < 4; ++r)
          Obuf[(qh * 32 + qn * 16 + quad * 4 + r) * 65 + dt * 16 + mrow] =
              oacc[dt][qn][r];
  }
  __syncthreads();
  if (kh2 == 0) {
#pragma unroll
    for (int qn = 0; qn < 2; ++qn) {
#pragma unroll
      for (int r = 0; r < 4; ++r) {
        int qrow = qh * 32 + qn * 16 + quad * 4 + r;
        float l = lbuf[qrow] + lbuf[64 + qrow];
        int qg = b * 2048 + q0 + qrow;
        float inv = qmask[qg] / l;
#pragma unroll
        for (int dt = 0; dt < 4; ++dt) {
          int idx = qg * 512 + h * 64 + dt * 16 + mrow;
          out[idx] =
              (oacc[dt][qn][r] + Obuf[qrow * 65 + dt * 16 + mrow]) * inv +
              queries[idx];
        }
      }
    }
  }
}

// ---------------------------------------------------------------------------
// Kernel 4: LayerNorm (unbiased std, eps added to std), in-place on d_out.
// ---------------------------------------------------------------------------
__global__ __launch_bounds__(256) void ln_kernel(float* __restrict__ out,
                                                 const float* __restrict__ gamma,
                                                 const float* __restrict__ beta) {
  int row = blockIdx.x * 4 + (threadIdx.x >> 6);
  int lane = threadIdx.x & 63;
  float* p = out + row * 512;
  float4 v1 = ((const float4*)p)[lane];
  float4 v2 = ((const float4*)p)[64 + lane];
  float s = v1.x + v1.y + v1.z + v1.w + v2.x + v2.y + v2.z + v2.w;
  float sq = v1.x * v1.x + v1.y * v1.y + v1.z * v1.z + v1.w * v1.w +
             v2.x * v2.x + v2.y * v2.y + v2.z * v2.z + v2.w * v2.w;
#pragma unroll
  for (int off = 32; off > 0; off >>= 1) {
    s += __shfl_xor(s, off);
    sq += __shfl_xor(sq, off);
  }
  float mean = s * (1.f / 512.f);
  float var = fmaxf((sq - 512.f * mean * mean) * (1.f / 511.f), 0.f);
  float inv = 1.f / (sqrtf(var) + 1e-8f);
  float4 g1 = ((const float4*)gamma)[lane];
  float4 g2 = ((const float4*)gamma)[64 + lane];
  float4 b1 = ((const float4*)beta)[lane];
  float4 b2 = ((const float4*)beta)[64 + lane];
  v1.x = g1.x * (v1.x - mean) * inv + b1.x;
  v1.y = g1.y * (v1.y - mean) * inv + b1.y;
  v1.z = g1.z * (v1.z - mean) * inv + b1.z;
  v1.w = g1.w * (v1.w - mean) * inv + b1.w;
  v2.x = g2.x * (v2.x - mean) * inv + b2.x;
  v2.y = g2.y * (v2.y - mean) * inv + b2.y;
  v2.z = g2.z * (v2.z - mean) * inv + b2.z;
  v2.w = g2.w * (v2.w - mean) * inv + b2.w;
  ((float4*)p)[lane] = v1;
  ((float4*)p)[64 + lane] = v2;
}

// ---------------------------------------------------------------------------
extern "C" void kernel_launch(void* const* d_in, const int* in_sizes, int n_in,
                              void* d_out, int out_size, void* d_ws, size_t ws_size,
                              hipStream_t stream) {
  (void)in_sizes; (void)n_in; (void)out_size; (void)ws_size;
  const float* queries = (const float*)d_in[0];
  const float* keys    = (const float*)d_in[1];
  const float* values  = (const float*)d_in[2];
  const float* Wq = (const float*)d_in[3];
  const float* bq = (const float*)d_in[4];
  const float* Wk = (const float*)d_in[5];
  const float* bk = (const float*)d_in[6];
  const float* Wv = (const float*)d_in[7];
  const float* bv = (const float*)d_in[8];
  const float* gamma = (const float*)d_in[9];
  const float* beta  = (const float*)d_in[10];
  float* out = (float*)d_out;

  char* ws = (char*)d_ws;
  unsigned short* Qb = (unsigned short*)(ws);                    // 8 MiB
  unsigned short* Kb = (unsigned short*)(ws + 8 * 1024 * 1024);  // 8 MiB
  unsigned short* Vt = (unsigned short*)(ws + 16 * 1024 * 1024); // 8 MiB
  unsigned short* Wt = (unsigned short*)(ws + 24 * 1024 * 1024); // 1.5 MiB
  unsigned short* Xbv = (unsigned short*)(ws + 26 * 1024 * 1024); // 8 MiB
  float* qmask = (float*)(ws + 34 * 1024 * 1024);
  float* kbias = qmask + 8192;

  // Xb for queries/keys staged in d_out (16 MiB, dead until attn writes it)
  unsigned short* Xbq = (unsigned short*)d_out;
  unsigned short* Xbk = Xbq + 4194304;

  wt_kernel<<<384, 256, 0, stream>>>(Wq, Wk, Wv, Wt);
  xcvt_kernel<<<6144, 256, 0, stream>>>(queries, keys, values, Xbq, Xbk, Xbv,
                                        qmask, kbias);
  proj_kernel<<<dim3(192, 4), 256, 0, stream>>>(Xbq, Xbk, Xbv, bq, bk, bv,
                                                Wt, Qb, Kb, Vt);
  attn_kernel<<<dim3(32, 32), 256, 0, stream>>>(Qb, Kb, Vt, qmask, kbias,
                                                queries, out);
  ln_kernel<<<2048, 256, 0, stream>>>(out, gamma, beta);
}

// Round 3
// 189.954 us; speedup vs baseline: 1.3159x; 1.3159x over previous
//
#include <hip/hip_runtime.h>

// R10: attn rebuilt as 8-wave q-owner: 512 thr, q-tile 128, each wave owns
// 16 q rows outright (no key split -> no cross-wave combine, no Obuf/lbuf).
// Per-wave state ~110 VGPR -> launch_bounds(512,4) cap 128 is safe (R8/R9's
// spills came from ~135-reg bodies under the same cap: VGPR=64 + ~20MB
// scratch writes in counters). K+V double-buffered LDS 64 KB -> 2 blocks/CU
// = 16 waves/CU = 4/SIMD (2x R7). kbias C-init kept; l row-sum via one MFMA
// vs ones (C-layout lands l[quad*4+r] exactly in output row layout ->
// epilogue has zero shuffles/LDS). Grid (hb,qt): same-hb blocks share XCD.
// proj back to cap-170 (256,3) -- its ~125-reg body was marginal at cap 128.

typedef __attribute__((ext_vector_type(8))) __bf16 bf16x8;
typedef __attribute__((ext_vector_type(4))) float f32x4;

#if __has_builtin(__builtin_amdgcn_exp2f)
#define EXP2F __builtin_amdgcn_exp2f
#else
#define EXP2F exp2f
#endif

#define QSCALE (0.125f * 1.4426950408889634f)  // fold /sqrt(64) and ln->log2

__device__ __forceinline__ unsigned short f2bf(float f) {
  return __builtin_bit_cast(unsigned short, (__bf16)f);
}
__device__ __forceinline__ unsigned pk2(float a, float b) {
  return (unsigned)f2bf(a) | ((unsigned)f2bf(b) << 16);
}
__device__ __forceinline__ f32x4 mfma16(bf16x8 a, bf16x8 b, f32x4 c) {
  return __builtin_amdgcn_mfma_f32_16x16x32_bf16(a, b, c, 0, 0, 0);
}
__device__ __forceinline__ bf16x8 ld_bf8(const unsigned short* p) {
  return *(const bf16x8*)p;
}
// async global->LDS, 16 B per lane; LDS dst is wave-uniform base + lane*16
__device__ __forceinline__ void g2l16(const void* g, void* l) {
  __builtin_amdgcn_global_load_lds(
      (const __attribute__((address_space(1))) void*)g,
      (__attribute__((address_space(3))) void*)l, 16, 0, 0);
}

// ---------------------------------------------------------------------------
// Kernel 1: transpose + convert the three 512x512 weight matrices to bf16,
// layout Wt[z][n][k] (n-major) so MFMA B-fragments read contiguous k.
// ---------------------------------------------------------------------------
__global__ __launch_bounds__(256) void wt_kernel(const float* __restrict__ Wq,
                                                 const float* __restrict__ Wk,
                                                 const float* __restrict__ Wv,
                                                 unsigned short* __restrict__ Wt) {
  int idx = blockIdx.x * 256 + threadIdx.x;
  int o = idx * 8;
  int z = o >> 18;
  int rem = o & 262143;
  int n = rem >> 9;
  int k0 = rem & 511;
  const float* W = (z == 0) ? Wq : ((z == 1) ? Wk : Wv);
  unsigned int w[4];
#pragma unroll
  for (int i = 0; i < 4; ++i) {
    unsigned short lo = f2bf(W[(k0 + 2 * i) * 512 + n]);
    unsigned short hi = f2bf(W[(k0 + 2 * i + 1) * 512 + n]);
    w[i] = (unsigned)lo | ((unsigned)hi << 16);
  }
  *(uint4*)(Wt + o) = make_uint4(w[0], w[1], w[2], w[3]);
}

// ---------------------------------------------------------------------------
// Kernel 1b: convert X (queries/keys/values) fp32->bf16 rows, and compute
// the padding masks from exact fp32 row sums: qmask (0/1, multiplicative)
// and kbias (0/-1e30, folded into the QK MFMA accumulator init).
// One wave per 512-float row; 6144 blocks x 4 rows.
// ---------------------------------------------------------------------------
__global__ __launch_bounds__(256) void xcvt_kernel(
    const float* __restrict__ Xq, const float* __restrict__ Xk,
    const float* __restrict__ Xv, unsigned short* __restrict__ Xbq,
    unsigned short* __restrict__ Xbk, unsigned short* __restrict__ Xbv,
    float* __restrict__ qmask, float* __restrict__ kbias) {
  int row = blockIdx.x * 4 + (threadIdx.x >> 6);
  int lane = threadIdx.x & 63;
  int z = row >> 13;
  int r = row & 8191;
  const float* X = (z == 0) ? Xq : ((z == 1) ? Xk : Xv);
  unsigned short* Xb = (z == 0) ? Xbq : ((z == 1) ? Xbk : Xbv);
  const float* p = X + r * 512 + lane * 8;
  f32x4 lo = *(const f32x4*)p;
  f32x4 hi = *(const f32x4*)(p + 4);
  *(uint4*)(Xb + r * 512 + lane * 8) =
      make_uint4(pk2(lo[0], lo[1]), pk2(lo[2], lo[3]), pk2(hi[0], hi[1]),
                 pk2(hi[2], hi[3]));
  if (z < 2) {
    float s = lo[0] + lo[1] + lo[2] + lo[3] + hi[0] + hi[1] + hi[2] + hi[3];
#pragma unroll
    for (int off = 1; off < 64; off <<= 1) s += __shfl_xor(s, off);
    if (lane == 0) {
      if (z == 0)
        qmask[r] = (s == 0.f) ? 0.f : 1.f;
      else
        kbias[r] = (s == 0.f) ? -1.0e30f : 0.f;
    }
  }
}

// ---------------------------------------------------------------------------
// Kernel 2: QKV projection, pure-bf16 double-buffered GEMM, ONE barrier per
// K-step. A and B staged [128][32] shorts with source-side XOR swizzle.
// Grid (192 m-blocks, 4 n-blocks); z = m-block/64. Tile 128x128, BK=32.
// V stored transposed with the permuted intra-32-key order
// (pos = quad*8 + sub*4 + r), matching attn's P register-repack k-order.
// ---------------------------------------------------------------------------
__global__ __launch_bounds__(256, 3) void proj_kernel(
    const unsigned short* __restrict__ Xbq, const unsigned short* __restrict__ Xbk,
    const unsigned short* __restrict__ Xbv, const float* __restrict__ bq,
    const float* __restrict__ bk, const float* __restrict__ bv,
    const unsigned short* __restrict__ Wt, unsigned short* __restrict__ Qb,
    unsigned short* __restrict__ Kb, unsigned short* __restrict__ Vt) {
  __shared__ unsigned short Asm[2][128][32];
  __shared__ unsigned short Bsm[2][128][32];

  int tid = threadIdx.x;
  int m0g = blockIdx.x * 128;
  int z = m0g >> 13;
  int m0 = m0g & 8191;
  int n0 = blockIdx.y * 128;
  const unsigned short* Xb = (z == 0) ? Xbq : ((z == 1) ? Xbk : Xbv);
  const float* bias = (z == 0) ? bq : ((z == 1) ? bk : bv);
  const unsigned short* Wz = Wt + z * 262144;

  int w = tid >> 6, lane = tid & 63;
  int wm = w >> 1, wn = w & 1;
  int mrow = lane & 15, quad = lane >> 4;

  // staging: row = tid>>2 (0..63; +64 in 2nd call), slot = tid&3 (16B),
  // source slot XOR-swizzled by (row>>1)&3; LDS stays linear (g2l16).
  int srow = tid >> 2, sslot = tid & 3;
  int sxs = sslot ^ ((srow >> 1) & 3);
  const unsigned short* gA = Xb + (m0 + srow) * 512 + sxs * 8;
  const unsigned short* gB = Wz + (n0 + srow) * 512 + sxs * 8;
  char* lA = (char*)&Asm[0][0][0] + tid * 16;
  char* lB = (char*)&Bsm[0][0][0] + tid * 16;

  // fragment read slot (un-swizzles; (row>>1)&3 == (mrow>>1)&3 here)
  int rs = (quad ^ ((mrow >> 1) & 3)) * 8;

  f32x4 zero = {0.f, 0.f, 0.f, 0.f};
  f32x4 acc[4][4];
#pragma unroll
  for (int i = 0; i < 4; ++i)
#pragma unroll
    for (int j = 0; j < 4; ++j) acc[i][j] = zero;

  // prologue: stage kc=0 into buf 0
  g2l16(gA, lA);
  g2l16(gA + 64 * 512, lA + 4096);
  g2l16(gB, lB);
  g2l16(gB + 64 * 512, lB + 4096);
  __syncthreads();

  for (int kc = 0; kc < 16; ++kc) {
    int cur = kc & 1;
    if (kc < 15) {
      int ko = (kc + 1) * 32;
      int nb = cur ^ 1;
      g2l16(gA + ko, lA + nb * 8192);
      g2l16(gA + ko + 64 * 512, lA + nb * 8192 + 4096);
      g2l16(gB + ko, lB + nb * 8192);
      g2l16(gB + ko + 64 * 512, lB + nb * 8192 + 4096);
    }
    bf16x8 af[4], bfr[4];
#pragma unroll
    for (int mt = 0; mt < 4; ++mt)
      af[mt] = ld_bf8(&Asm[cur][wm * 64 + mt * 16 + mrow][rs]);
#pragma unroll
    for (int nt = 0; nt < 4; ++nt)
      bfr[nt] = ld_bf8(&Bsm[cur][wn * 64 + nt * 16 + mrow][rs]);
#pragma unroll
    for (int mt = 0; mt < 4; ++mt)
#pragma unroll
      for (int nt = 0; nt < 4; ++nt)
        acc[mt][nt] = mfma16(af[mt], bfr[nt], acc[mt][nt]);
    __syncthreads();
  }

  if (z < 2) {
    unsigned short* dst = (z == 0) ? Qb : Kb;
    float sc = (z == 0) ? QSCALE : 1.0f;
#pragma unroll
    for (int nt = 0; nt < 4; ++nt) {
      int n = n0 + wn * 64 + nt * 16 + mrow;
      float bv_ = bias[n];
#pragma unroll
      for (int mt = 0; mt < 4; ++mt) {
        int m = m0 + wm * 64 + mt * 16 + quad * 4;
#pragma unroll
        for (int r = 0; r < 4; ++r) {
          float v = fmaxf(acc[mt][nt][r] + bv_, 0.f) * sc;
          dst[(m + r) * 512 + n] = f2bf(v);
        }
      }
    }
  } else {
    // V: permuted-transposed store (pos = quad*8 + (mt&1)*4 + r in 32-t group)
#pragma unroll
    for (int nt = 0; nt < 4; ++nt) {
      int n = n0 + wn * 64 + nt * 16 + mrow;
      int hh = n >> 6, jj = n & 63;
      float bv_ = bias[n];
#pragma unroll
      for (int mt = 0; mt < 4; ++mt) {
        int grow = m0 + wm * 64 + mt * 16 + quad * 4;
        int bb = grow >> 11, tl = grow & 2047;
        int pos = (tl & ~31) + quad * 8 + (mt & 1) * 4;
        float p0 = fmaxf(acc[mt][nt][0] + bv_, 0.f);
        float p1 = fmaxf(acc[mt][nt][1] + bv_, 0.f);
        float p2 = fmaxf(acc[mt][nt][2] + bv_, 0.f);
        float p3 = fmaxf(acc[mt][nt][3] + bv_, 0.f);
        *(uint2*)(Vt + ((hh * 4 + bb) * 64 + jj) * 2048 + pos) =
            make_uint2(pk2(p0, p1), pk2(p2, p3));
      }
    }
  }
}

// ---------------------------------------------------------------------------
// Kernel 3: attention, 8-wave q-owner. Grid (hb=32, qt=16); 512 threads;
// wave w owns q rows q0+w*16..+15 for head h: computes full 2048-key softmax
// row independently. 16 chunks of 128 keys; K+V double-buffered LDS (64 KB,
// XOR-swizzled staging, 8-cycle-optimal b128 reads); ONE barrier per chunk.
// QK: S^T = K*Q^T seeded with kbias (mask pre-folded). PV: O = P*V^T with P
// as A-operand (register repack; Vt permuted to match). l = P row-sum via
// MFMA vs ones: lacc[r] = l[q=quad*4+r] -- exactly the C row layout, so the
// epilogue is pure per-lane arithmetic (no shuffles, no LDS, no barrier).
// ---------------------------------------------------------------------------
__global__ __launch_bounds__(512, 4) void attn_kernel(
    const unsigned short* __restrict__ Qb, const unsigned short* __restrict__ Kb,
    const unsigned short* __restrict__ Vt, const float* __restrict__ qmask,
    const float* __restrict__ kbias, const float* __restrict__ queries,
    float* __restrict__ out) {
  __shared__ char smem[65536];
  unsigned short* KsmS = (unsigned short*)smem;            // [2][8192] shorts
  unsigned short* VsmS = (unsigned short*)(smem + 32768);  // [2][8192] shorts

  int hb = blockIdx.x;
  int qt = blockIdx.y;
  int h = hb >> 2, b = hb & 3;
  int q0 = qt * 128;
  int tid = threadIdx.x;
  int w = tid >> 6, lane = tid & 63;
  int mrow = lane & 15, quad = lane >> 4;
  int mlow = mrow & 7;

  // staging source pointers (XOR-swizzled slot->chunk):
  // K: rows tid>>3 in 0..63 (+64 in 2nd call), slot (tid&7)^(row&7)
  // V: rows tid>>4 in 0..31 (+32 in 2nd call), slot (tid&15)^(row&15)
  const unsigned short* gK =
      Kb + (b * 2048 + (tid >> 3)) * 512 + h * 64 + (((tid & 7) ^ ((tid >> 3) & 7)) * 8);
  const unsigned short* gV =
      Vt + (hb * 64 + (tid >> 4)) * 2048 + (((tid & 15) ^ ((tid >> 4) & 15)) * 8);

  // Q B-frags for this wave's 16 q rows: [n=q mrow][k=dh quad*8 (+32)]
  bf16x8 qf0, qf1;
  {
    const unsigned short* qp =
        Qb + (b * 2048 + q0 + w * 16 + mrow) * 512 + h * 64 + quad * 8;
    qf0 = ld_bf8(qp);
    qf1 = ld_bf8(qp + 32);
  }

  bf16x8 onev;
#pragma unroll
  for (int i = 0; i < 8; ++i) onev[i] = (__bf16)1.0f;

  f32x4 zero = {0.f, 0.f, 0.f, 0.f};
  f32x4 oacc[4];  // [dt]: col=dh dt*16+mrow, row=q quad*4+r
#pragma unroll
  for (int i = 0; i < 4; ++i) oacc[i] = zero;
  f32x4 lacc = zero;  // l[q=quad*4+r], replicated over cols

  const float* kmB = kbias + b * 2048 + quad * 4;

  // preload chunk 0 into buf 0
  g2l16(gK, &KsmS[tid * 8]);
  g2l16(gK + 64 * 512, &KsmS[4096 + tid * 8]);
  g2l16(gV, &VsmS[tid * 8]);
  g2l16(gV + 32 * 2048, &VsmS[4096 + tid * 8]);

  for (int it = 0; it < 16; ++it) {
    int bi = it & 1;
    int kb = it * 128;
    __syncthreads();  // drains staging DMA; buf bi ready

    if (it < 15) {
      int nb = 1 - bi;
      int nkb = kb + 128;
      g2l16(gK + nkb * 512, &KsmS[nb * 8192 + tid * 8]);
      g2l16(gK + (nkb + 64) * 512, &KsmS[nb * 8192 + 4096 + tid * 8]);
      g2l16(gV + nkb, &VsmS[nb * 8192 + tid * 8]);
      g2l16(gV + nkb + 32 * 2048, &VsmS[nb * 8192 + 4096 + tid * 8]);
    }

    const unsigned short* Kc = KsmS + bi * 8192;
    const unsigned short* Vc = VsmS + bi * 8192;

#pragma unroll
    for (int g = 0; g < 4; ++g) {
      f32x4 km0 = *(const f32x4*)(kmB + kb + g * 32);
      f32x4 km1 = *(const f32x4*)(kmB + kb + g * 32 + 16);
      bf16x8 kf00 = ld_bf8(&Kc[(g * 32 + mrow) * 64 + ((quad) ^ mlow) * 8]);
      bf16x8 kf01 = ld_bf8(&Kc[(g * 32 + mrow) * 64 + ((4 + quad) ^ mlow) * 8]);
      bf16x8 kf10 = ld_bf8(&Kc[(g * 32 + 16 + mrow) * 64 + ((quad) ^ mlow) * 8]);
      bf16x8 kf11 = ld_bf8(&Kc[(g * 32 + 16 + mrow) * 64 + ((4 + quad) ^ mlow) * 8]);
      bf16x8 vfg[4];
#pragma unroll
      for (int dt = 0; dt < 4; ++dt)
        vfg[dt] = ld_bf8(&Vc[(dt * 16 + mrow) * 128 + ((g * 4 + quad) ^ mrow) * 8]);

      f32x4 s0 = mfma16(kf00, qf0, km0);
      s0 = mfma16(kf01, qf1, s0);
      f32x4 s1 = mfma16(kf10, qf0, km1);
      s1 = mfma16(kf11, qf1, s1);

      f32x4 p0, p1;
#pragma unroll
      for (int r = 0; r < 4; ++r) {
        p0[r] = EXP2F(s0[r]);
        p1[r] = EXP2F(s1[r]);
      }
      bf16x8 pf = __builtin_bit_cast(
          bf16x8, make_uint4(pk2(p0[0], p0[1]), pk2(p0[2], p0[3]),
                             pk2(p1[0], p1[1]), pk2(p1[2], p1[3])));
      lacc = mfma16(pf, onev, lacc);
#pragma unroll
      for (int dt = 0; dt < 4; ++dt)
        oacc[dt] = mfma16(pf, vfg[dt], oacc[dt]);
    }
  }

  // --- epilogue: pure per-lane (lacc[r] is already l for row quad*4+r)
#pragma unroll
  for (int r = 0; r < 4; ++r) {
    int qg = b * 2048 + q0 + w * 16 + quad * 4 + r;
    float inv = qmask[qg] / lacc[r];
    const float* qsrc = queries + qg * 512 + h * 64 + mrow;
    float* od = out + qg * 512 + h * 64 + mrow;
#pragma unroll
    for (int dt = 0; dt < 4; ++dt)
      od[dt * 16] = oacc[dt][r] * inv + qsrc[dt * 16];
  }
}

// ---------------------------------------------------------------------------
// Kernel 4: LayerNorm (unbiased std, eps added to std), in-place on d_out.
// ---------------------------------------------------------------------------
__global__ __launch_bounds__(256) void ln_kernel(float* __restrict__ out,
                                                 const float* __restrict__ gamma,
                                                 const float* __restrict__ beta) {
  int row = blockIdx.x * 4 + (threadIdx.x >> 6);
  int lane = threadIdx.x & 63;
  float* p = out + row * 512;
  float4 v1 = ((const float4*)p)[lane];
  float4 v2 = ((const float4*)p)[64 + lane];
  float s = v1.x + v1.y + v1.z + v1.w + v2.x + v2.y + v2.z + v2.w;
  float sq = v1.x * v1.x + v1.y * v1.y + v1.z * v1.z + v1.w * v1.w +
             v2.x * v2.x + v2.y * v2.y + v2.z * v2.z + v2.w * v2.w;
#pragma unroll
  for (int off = 32; off > 0; off >>= 1) {
    s += __shfl_xor(s, off);
    sq += __shfl_xor(sq, off);
  }
  float mean = s * (1.f / 512.f);
  float var = fmaxf((sq - 512.f * mean * mean) * (1.f / 511.f), 0.f);
  float inv = 1.f / (sqrtf(var) + 1e-8f);
  float4 g1 = ((const float4*)gamma)[lane];
  float4 g2 = ((const float4*)gamma)[64 + lane];
  float4 b1 = ((const float4*)beta)[lane];
  float4 b2 = ((const float4*)beta)[64 + lane];
  v1.x = g1.x * (v1.x - mean) * inv + b1.x;
  v1.y = g1.y * (v1.y - mean) * inv + b1.y;
  v1.z = g1.z * (v1.z - mean) * inv + b1.z;
  v1.w = g1.w * (v1.w - mean) * inv + b1.w;
  v2.x = g2.x * (v2.x - mean) * inv + b2.x;
  v2.y = g2.y * (v2.y - mean) * inv + b2.y;
  v2.z = g2.z * (v2.z - mean) * inv + b2.z;
  v2.w = g2.w * (v2.w - mean) * inv + b2.w;
  ((float4*)p)[lane] = v1;
  ((float4*)p)[64 + lane] = v2;
}

// ---------------------------------------------------------------------------
extern "C" void kernel_launch(void* const* d_in, const int* in_sizes, int n_in,
                              void* d_out, int out_size, void* d_ws, size_t ws_size,
                              hipStream_t stream) {
  (void)in_sizes; (void)n_in; (void)out_size; (void)ws_size;
  const float* queries = (const float*)d_in[0];
  const float* keys    = (const float*)d_in[1];
  const float* values  = (const float*)d_in[2];
  const float* Wq = (const float*)d_in[3];
  const float* bq = (const float*)d_in[4];
  const float* Wk = (const float*)d_in[5];
  const float* bk = (const float*)d_in[6];
  const float* Wv = (const float*)d_in[7];
  const float* bv = (const float*)d_in[8];
  const float* gamma = (const float*)d_in[9];
  const float* beta  = (const float*)d_in[10];
  float* out = (float*)d_out;

  char* ws = (char*)d_ws;
  unsigned short* Qb = (unsigned short*)(ws);                    // 8 MiB
  unsigned short* Kb = (unsigned short*)(ws + 8 * 1024 * 1024);  // 8 MiB
  unsigned short* Vt = (unsigned short*)(ws + 16 * 1024 * 1024); // 8 MiB
  unsigned short* Wt = (unsigned short*)(ws + 24 * 1024 * 1024); // 1.5 MiB
  unsigned short* Xbv = (unsigned short*)(ws + 26 * 1024 * 1024); // 8 MiB
  float* qmask = (float*)(ws + 34 * 1024 * 1024);
  float* kbias = qmask + 8192;

  // Xb for queries/keys staged in d_out (16 MiB, dead until attn writes it)
  unsigned short* Xbq = (unsigned short*)d_out;
  unsigned short* Xbk = Xbq + 4194304;

  wt_kernel<<<384, 256, 0, stream>>>(Wq, Wk, Wv, Wt);
  xcvt_kernel<<<6144, 256, 0, stream>>>(queries, keys, values, Xbq, Xbk, Xbv,
                                        qmask, kbias);
  proj_kernel<<<dim3(192, 4), 256, 0, stream>>>(Xbq, Xbk, Xbv, bq, bk, bv,
                                                Wt, Qb, Kb, Vt);
  attn_kernel<<<dim3(32, 16), 512, 0, stream>>>(Qb, Kb, Vt, qmask, kbias,
                                                queries, out);
  ln_kernel<<<2048, 256, 0, stream>>>(out, gamma, beta);
}

// Round 5
// 187.200 us; speedup vs baseline: 1.3353x; 1.0147x over previous
//
#include <hip/hip_runtime.h>

// R12 = R11 re-run (previous round hit an infra "container failed twice";
// no signal about the kernel). attn: q-owner kept (no cross-wave combine;
// kbias C-init; MFMA-ones l; per-lane epilogue) but w_q=32 per wave:
// 256 thr / 4 waves / q-tile 128. Per g-group: 18 MFMA per 8 ds_read_b128
// (2x R10's intensity) -> LDS traffic halves (~1 GB, 15 us floor vs 19 us
// MFMA floor). cap-256 VGPR (launch_bounds(256,2)) leaves room to REGISTER-
// double-buffer the per-g K/V fragments + kbias: g+1's ds_reads issue while
// g computes, hiding ~120cy LDS latency inside the chunk. Staging = R7's
// proven 256-thr code; fragment reads = R10's (0 bank conflicts measured).
// Grid (32,16): same-(h,b) blocks share an XCD (K/V L2-local).

typedef __attribute__((ext_vector_type(8))) __bf16 bf16x8;
typedef __attribute__((ext_vector_type(4))) float f32x4;

#if __has_builtin(__builtin_amdgcn_exp2f)
#define EXP2F __builtin_amdgcn_exp2f
#else
#define EXP2F exp2f
#endif

#define QSCALE (0.125f * 1.4426950408889634f)  // fold /sqrt(64) and ln->log2

__device__ __forceinline__ unsigned short f2bf(float f) {
  return __builtin_bit_cast(unsigned short, (__bf16)f);
}
__device__ __forceinline__ unsigned pk2(float a, float b) {
  return (unsigned)f2bf(a) | ((unsigned)f2bf(b) << 16);
}
__device__ __forceinline__ f32x4 mfma16(bf16x8 a, bf16x8 b, f32x4 c) {
  return __builtin_amdgcn_mfma_f32_16x16x32_bf16(a, b, c, 0, 0, 0);
}
__device__ __forceinline__ bf16x8 ld_bf8(const unsigned short* p) {
  return *(const bf16x8*)p;
}
// async global->LDS, 16 B per lane; LDS dst is wave-uniform base + lane*16
__device__ __forceinline__ void g2l16(const void* g, void* l) {
  __builtin_amdgcn_global_load_lds(
      (const __attribute__((address_space(1))) void*)g,
      (__attribute__((address_space(3))) void*)l, 16, 0, 0);
}

// ---------------------------------------------------------------------------
// Kernel 1: transpose + convert the three 512x512 weight matrices to bf16,
// layout Wt[z][n][k] (n-major) so MFMA B-fragments read contiguous k.
// ---------------------------------------------------------------------------
__global__ __launch_bounds__(256) void wt_kernel(const float* __restrict__ Wq,
                                                 const float* __restrict__ Wk,
                                                 const float* __restrict__ Wv,
                                                 unsigned short* __restrict__ Wt) {
  int idx = blockIdx.x * 256 + threadIdx.x;
  int o = idx * 8;
  int z = o >> 18;
  int rem = o & 262143;
  int n = rem >> 9;
  int k0 = rem & 511;
  const float* W = (z == 0) ? Wq : ((z == 1) ? Wk : Wv);
  unsigned int w[4];
#pragma unroll
  for (int i = 0; i < 4; ++i) {
    unsigned short lo = f2bf(W[(k0 + 2 * i) * 512 + n]);
    unsigned short hi = f2bf(W[(k0 + 2 * i + 1) * 512 + n]);
    w[i] = (unsigned)lo | ((unsigned)hi << 16);
  }
  *(uint4*)(Wt + o) = make_uint4(w[0], w[1], w[2], w[3]);
}

// ---------------------------------------------------------------------------
// Kernel 1b: convert X (queries/keys/values) fp32->bf16 rows, and compute
// the padding masks from exact fp32 row sums: qmask (0/1, multiplicative)
// and kbias (0/-1e30, folded into the QK MFMA accumulator init).
// One wave per 512-float row; 6144 blocks x 4 rows.
// ---------------------------------------------------------------------------
__global__ __launch_bounds__(256) void xcvt_kernel(
    const float* __restrict__ Xq, const float* __restrict__ Xk,
    const float* __restrict__ Xv, unsigned short* __restrict__ Xbq,
    unsigned short* __restrict__ Xbk, unsigned short* __restrict__ Xbv,
    float* __restrict__ qmask, float* __restrict__ kbias) {
  int row = blockIdx.x * 4 + (threadIdx.x >> 6);
  int lane = threadIdx.x & 63;
  int z = row >> 13;
  int r = row & 8191;
  const float* X = (z == 0) ? Xq : ((z == 1) ? Xk : Xv);
  unsigned short* Xb = (z == 0) ? Xbq : ((z == 1) ? Xbk : Xbv);
  const float* p = X + r * 512 + lane * 8;
  f32x4 lo = *(const f32x4*)p;
  f32x4 hi = *(const f32x4*)(p + 4);
  *(uint4*)(Xb + r * 512 + lane * 8) =
      make_uint4(pk2(lo[0], lo[1]), pk2(lo[2], lo[3]), pk2(hi[0], hi[1]),
                 pk2(hi[2], hi[3]));
  if (z < 2) {
    float s = lo[0] + lo[1] + lo[2] + lo[3] + hi[0] + hi[1] + hi[2] + hi[3];
#pragma unroll
    for (int off = 1; off < 64; off <<= 1) s += __shfl_xor(s, off);
    if (lane == 0) {
      if (z == 0)
        qmask[r] = (s == 0.f) ? 0.f : 1.f;
      else
        kbias[r] = (s == 0.f) ? -1.0e30f : 0.f;
    }
  }
}

// ---------------------------------------------------------------------------
// Kernel 2: QKV projection, pure-bf16 double-buffered GEMM, ONE barrier per
// K-step. A and B staged [128][32] shorts with source-side XOR swizzle.
// Grid (192 m-blocks, 4 n-blocks); z = m-block/64. Tile 128x128, BK=32.
// V stored transposed with the permuted intra-32-key order
// (pos = quad*8 + sub*4 + r), matching attn's P register-repack k-order.
// ---------------------------------------------------------------------------
__global__ __launch_bounds__(256, 3) void proj_kernel(
    const unsigned short* __restrict__ Xbq, const unsigned short* __restrict__ Xbk,
    const unsigned short* __restrict__ Xbv, const float* __restrict__ bq,
    const float* __restrict__ bk, const float* __restrict__ bv,
    const unsigned short* __restrict__ Wt, unsigned short* __restrict__ Qb,
    unsigned short* __restrict__ Kb, unsigned short* __restrict__ Vt) {
  __shared__ unsigned short Asm[2][128][32];
  __shared__ unsigned short Bsm[2][128][32];

  int tid = threadIdx.x;
  int m0g = blockIdx.x * 128;
  int z = m0g >> 13;
  int m0 = m0g & 8191;
  int n0 = blockIdx.y * 128;
  const unsigned short* Xb = (z == 0) ? Xbq : ((z == 1) ? Xbk : Xbv);
  const float* bias = (z == 0) ? bq : ((z == 1) ? bk : bv);
  const unsigned short* Wz = Wt + z * 262144;

  int w = tid >> 6, lane = tid & 63;
  int wm = w >> 1, wn = w & 1;
  int mrow = lane & 15, quad = lane >> 4;

  // staging: row = tid>>2 (0..63; +64 in 2nd call), slot = tid&3 (16B),
  // source slot XOR-swizzled by (row>>1)&3; LDS stays linear (g2l16).
  int srow = tid >> 2, sslot = tid & 3;
  int sxs = sslot ^ ((srow >> 1) & 3);
  const unsigned short* gA = Xb + (m0 + srow) * 512 + sxs * 8;
  const unsigned short* gB = Wz + (n0 + srow) * 512 + sxs * 8;
  char* lA = (char*)&Asm[0][0][0] + tid * 16;
  char* lB = (char*)&Bsm[0][0][0] + tid * 16;

  // fragment read slot (un-swizzles; (row>>1)&3 == (mrow>>1)&3 here)
  int rs = (quad ^ ((mrow >> 1) & 3)) * 8;

  f32x4 zero = {0.f, 0.f, 0.f, 0.f};
  f32x4 acc[4][4];
#pragma unroll
  for (int i = 0; i < 4; ++i)
#pragma unroll
    for (int j = 0; j < 4; ++j) acc[i][j] = zero;

  // prologue: stage kc=0 into buf 0
  g2l16(gA, lA);
  g2l16(gA + 64 * 512, lA + 4096);
  g2l16(gB, lB);
  g2l16(gB + 64 * 512, lB + 4096);
  __syncthreads();

  for (int kc = 0; kc < 16; ++kc) {
    int cur = kc & 1;
    if (kc < 15) {
      int ko = (kc + 1) * 32;
      int nb = cur ^ 1;
      g2l16(gA + ko, lA + nb * 8192);
      g2l16(gA + ko + 64 * 512, lA + nb * 8192 + 4096);
      g2l16(gB + ko, lB + nb * 8192);
      g2l16(gB + ko + 64 * 512, lB + nb * 8192 + 4096);
    }
    bf16x8 af[4], bfr[4];
#pragma unroll
    for (int mt = 0; mt < 4; ++mt)
      af[mt] = ld_bf8(&Asm[cur][wm * 64 + mt * 16 + mrow][rs]);
#pragma unroll
    for (int nt = 0; nt < 4; ++nt)
      bfr[nt] = ld_bf8(&Bsm[cur][wn * 64 + nt * 16 + mrow][rs]);
#pragma unroll
    for (int mt = 0; mt < 4; ++mt)
#pragma unroll
      for (int nt = 0; nt < 4; ++nt)
        acc[mt][nt] = mfma16(af[mt], bfr[nt], acc[mt][nt]);
    __syncthreads();
  }

  if (z < 2) {
    unsigned short* dst = (z == 0) ? Qb : Kb;
    float sc = (z == 0) ? QSCALE : 1.0f;
#pragma unroll
    for (int nt = 0; nt < 4; ++nt) {
      int n = n0 + wn * 64 + nt * 16 + mrow;
      float bv_ = bias[n];
#pragma unroll
      for (int mt = 0; mt < 4; ++mt) {
        int m = m0 + wm * 64 + mt * 16 + quad * 4;
#pragma unroll
        for (int r = 0; r < 4; ++r) {
          float v = fmaxf(acc[mt][nt][r] + bv_, 0.f) * sc;
          dst[(m + r) * 512 + n] = f2bf(v);
        }
      }
    }
  } else {
    // V: permuted-transposed store (pos = quad*8 + (mt&1)*4 + r in 32-t group)
#pragma unroll
    for (int nt = 0; nt < 4; ++nt) {
      int n = n0 + wn * 64 + nt * 16 + mrow;
      int hh = n >> 6, jj = n & 63;
      float bv_ = bias[n];
#pragma unroll
      for (int mt = 0; mt < 4; ++mt) {
        int grow = m0 + wm * 64 + mt * 16 + quad * 4;
        int bb = grow >> 11, tl = grow & 2047;
        int pos = (tl & ~31) + quad * 8 + (mt & 1) * 4;
        float p0 = fmaxf(acc[mt][nt][0] + bv_, 0.f);
        float p1 = fmaxf(acc[mt][nt][1] + bv_, 0.f);
        float p2 = fmaxf(acc[mt][nt][2] + bv_, 0.f);
        float p3 = fmaxf(acc[mt][nt][3] + bv_, 0.f);
        *(uint2*)(Vt + ((hh * 4 + bb) * 64 + jj) * 2048 + pos) =
            make_uint2(pk2(p0, p1), pk2(p2, p3));
      }
    }
  }
}

// ---------------------------------------------------------------------------
// Kernel 3: attention, 4-wave q-owner, w_q=32. Grid (hb=32, qt=16); 256 thr;
// wave w owns q rows q0+w*32..+31: full 2048-key softmax rows independently.
// 16 chunks of 128 keys; K+V double-buffered LDS (64 KB, XOR-swizzled
// staging; conflict-free reads per R10 counters); ONE barrier per chunk.
// Per-g K/V fragments + kbias register-double-buffered (g+1 ds_reads issue
// during g's compute). QK: S^T = K*Q^T seeded with kbias. PV: O = P*V^T, P
// as A-operand (register repack; Vt permuted to match). l via MFMA vs ones:
// lacc[qn][r] = l[q], exactly the C row layout -> per-lane epilogue.
// ---------------------------------------------------------------------------
__global__ __launch_bounds__(256, 2) void attn_kernel(
    const unsigned short* __restrict__ Qb, const unsigned short* __restrict__ Kb,
    const unsigned short* __restrict__ Vt, const float* __restrict__ qmask,
    const float* __restrict__ kbias, const float* __restrict__ queries,
    float* __restrict__ out) {
  __shared__ char smem[65536];
  unsigned short* KsmS = (unsigned short*)smem;            // [2][8192] shorts
  unsigned short* VsmS = (unsigned short*)(smem + 32768);  // [2][8192] shorts

  int hb = blockIdx.x;
  int qt = blockIdx.y;
  int h = hb >> 2, b = hb & 3;
  int q0 = qt * 128;
  int tid = threadIdx.x;
  int w = tid >> 6, lane = tid & 63;
  int mrow = lane & 15, quad = lane >> 4;
  int mlow = mrow & 7;

  // staging source pointers (XOR-swizzled slot->chunk), 256-thr (R7 form):
  // K: rows tid>>3 in 0..31 (4 j-steps of 32), slot (tid&7)^(row&7)
  // V: rows tid>>4 in 0..15 (4 j-steps of 16), slot (tid&15)^(row&15)
  const unsigned short* gK =
      Kb + (b * 2048 + (tid >> 3)) * 512 + h * 64 + (((tid & 7) ^ ((tid >> 3) & 7)) * 8);
  const unsigned short* gV =
      Vt + (hb * 64 + (tid >> 4)) * 2048 + (((tid & 15) ^ ((tid >> 4) & 15)) * 8);

  // Q B-frags for this wave's 32 q rows: [qn][k-half]
  bf16x8 qf[2][2];
  {
    const unsigned short* qp =
        Qb + (b * 2048 + q0 + w * 32 + mrow) * 512 + h * 64 + quad * 8;
#pragma unroll
    for (int qn = 0; qn < 2; ++qn) {
      qf[qn][0] = ld_bf8(qp + qn * 8192);
      qf[qn][1] = ld_bf8(qp + qn * 8192 + 32);
    }
  }

  bf16x8 onev;
#pragma unroll
  for (int i = 0; i < 8; ++i) onev[i] = (__bf16)1.0f;

  f32x4 zero = {0.f, 0.f, 0.f, 0.f};
  f32x4 oacc[4][2];  // [dt][qn]: col=dh dt*16+mrow, row=q quad*4+r
#pragma unroll
  for (int i = 0; i < 4; ++i)
#pragma unroll
    for (int j = 0; j < 2; ++j) oacc[i][j] = zero;
  f32x4 lacc[2] = {zero, zero};  // l[q], replicated over cols

  const float* kmB = kbias + b * 2048 + quad * 4;

  // preload chunk 0 into buf 0
#pragma unroll
  for (int j = 0; j < 4; ++j) {
    g2l16(gK + j * 32 * 512, &KsmS[j * 2048 + tid * 8]);
    g2l16(gV + j * 16 * 2048, &VsmS[j * 2048 + tid * 8]);
  }

  for (int it = 0; it < 16; ++it) {
    int bi = it & 1;
    int kb = it * 128;
    __syncthreads();  // drains staging DMA; buf bi ready

    if (it < 15) {
      int nb = 1 - bi;
      int nkb = kb + 128;
#pragma unroll
      for (int j = 0; j < 4; ++j) {
        g2l16(gK + (nkb + j * 32) * 512, &KsmS[nb * 8192 + j * 2048 + tid * 8]);
        g2l16(gV + nkb + j * 16 * 2048, &VsmS[nb * 8192 + j * 2048 + tid * 8]);
      }
    }

    const unsigned short* Kc = KsmS + bi * 8192;
    const unsigned short* Vc = VsmS + bi * 8192;

    // register-double-buffered per-g fragments (fully unrolled -> renamed)
    bf16x8 kf[2][4], vf[2][4];
    f32x4 km[2][2];
    auto ldg = [&](int gi, int sl) {
      km[sl][0] = *(const f32x4*)(kmB + kb + gi * 32);
      km[sl][1] = *(const f32x4*)(kmB + kb + gi * 32 + 16);
      kf[sl][0] = ld_bf8(&Kc[(gi * 32 + mrow) * 64 + (quad ^ mlow) * 8]);
      kf[sl][1] = ld_bf8(&Kc[(gi * 32 + mrow) * 64 + ((4 + quad) ^ mlow) * 8]);
      kf[sl][2] = ld_bf8(&Kc[(gi * 32 + 16 + mrow) * 64 + (quad ^ mlow) * 8]);
      kf[sl][3] = ld_bf8(&Kc[(gi * 32 + 16 + mrow) * 64 + ((4 + quad) ^ mlow) * 8]);
#pragma unroll
      for (int dt = 0; dt < 4; ++dt)
        vf[sl][dt] =
            ld_bf8(&Vc[(dt * 16 + mrow) * 128 + ((gi * 4 + quad) ^ mrow) * 8]);
    };

    ldg(0, 0);
#pragma unroll
    for (int g = 0; g < 4; ++g) {
      int cb = g & 1;
      if (g < 3) ldg(g + 1, cb ^ 1);
#pragma unroll
      for (int qn = 0; qn < 2; ++qn) {
        f32x4 s0 = mfma16(kf[cb][0], qf[qn][0], km[cb][0]);
        s0 = mfma16(kf[cb][1], qf[qn][1], s0);
        f32x4 s1 = mfma16(kf[cb][2], qf[qn][0], km[cb][1]);
        s1 = mfma16(kf[cb][3], qf[qn][1], s1);
        f32x4 p0, p1;
#pragma unroll
        for (int r = 0; r < 4; ++r) {
          p0[r] = EXP2F(s0[r]);
          p1[r] = EXP2F(s1[r]);
        }
        bf16x8 pf = __builtin_bit_cast(
            bf16x8, make_uint4(pk2(p0[0], p0[1]), pk2(p0[2], p0[3]),
                               pk2(p1[0], p1[1]), pk2(p1[2], p1[3])));
        lacc[qn] = mfma16(pf, onev, lacc[qn]);
#pragma unroll
        for (int dt = 0; dt < 4; ++dt)
          oacc[dt][qn] = mfma16(pf, vf[cb][dt], oacc[dt][qn]);
      }
    }
  }

  // --- epilogue: pure per-lane (lacc[qn][r] is l for row qn*16+quad*4+r)
#pragma unroll
  for (int qn = 0; qn < 2; ++qn) {
#pragma unroll
    for (int r = 0; r < 4; ++r) {
      int qg = b * 2048 + q0 + w * 32 + qn * 16 + quad * 4 + r;
      float inv = qmask[qg] / lacc[qn][r];
      const float* qsrc = queries + qg * 512 + h * 64 + mrow;
      float* od = out + qg * 512 + h * 64 + mrow;
#pragma unroll
      for (int dt = 0; dt < 4; ++dt)
        od[dt * 16] = oacc[dt][qn][r] * inv + qsrc[dt * 16];
    }
  }
}

// ---------------------------------------------------------------------------
// Kernel 4: LayerNorm (unbiased std, eps added to std), in-place on d_out.
// ---------------------------------------------------------------------------
__global__ __launch_bounds__(256) void ln_kernel(float* __restrict__ out,
                                                 const float* __restrict__ gamma,
                                                 const float* __restrict__ beta) {
  int row = blockIdx.x * 4 + (threadIdx.x >> 6);
  int lane = threadIdx.x & 63;
  float* p = out + row * 512;
  float4 v1 = ((const float4*)p)[lane];
  float4 v2 = ((const float4*)p)[64 + lane];
  float s = v1.x + v1.y + v1.z + v1.w + v2.x + v2.y + v2.z + v2.w;
  float sq = v1.x * v1.x + v1.y * v1.y + v1.z * v1.z + v1.w * v1.w +
             v2.x * v2.x + v2.y * v2.y + v2.z * v2.z + v2.w * v2.w;
#pragma unroll
  for (int off = 32; off > 0; off >>= 1) {
    s += __shfl_xor(s, off);
    sq += __shfl_xor(sq, off);
  }
  float mean = s * (1.f / 512.f);
  float var = fmaxf((sq - 512.f * mean * mean) * (1.f / 511.f), 0.f);
  float inv = 1.f / (sqrtf(var) + 1e-8f);
  float4 g1 = ((const float4*)gamma)[lane];
  float4 g2 = ((const float4*)gamma)[64 + lane];
  float4 b1 = ((const float4*)beta)[lane];
  float4 b2 = ((const float4*)beta)[64 + lane];
  v1.x = g1.x * (v1.x - mean) * inv + b1.x;
  v1.y = g1.y * (v1.y - mean) * inv + b1.y;
  v1.z = g1.z * (v1.z - mean) * inv + b1.z;
  v1.w = g1.w * (v1.w - mean) * inv + b1.w;
  v2.x = g2.x * (v2.x - mean) * inv + b2.x;
  v2.y = g2.y * (v2.y - mean) * inv + b2.y;
  v2.z = g2.z * (v2.z - mean) * inv + b2.z;
  v2.w = g2.w * (v2.w - mean) * inv + b2.w;
  ((float4*)p)[lane] = v1;
  ((float4*)p)[64 + lane] = v2;
}

// ---------------------------------------------------------------------------
extern "C" void kernel_launch(void* const* d_in, const int* in_sizes, int n_in,
                              void* d_out, int out_size, void* d_ws, size_t ws_size,
                              hipStream_t stream) {
  (void)in_sizes; (void)n_in; (void)out_size; (void)ws_size;
  const float* queries = (const float*)d_in[0];
  const float* keys    = (const float*)d_in[1];
  const float* values  = (const float*)d_in[2];
  const float* Wq = (const float*)d_in[3];
  const float* bq = (const float*)d_in[4];
  const float* Wk = (const float*)d_in[5];
  const float* bk = (const float*)d_in[6];
  const float* Wv = (const float*)d_in[7];
  const float* bv = (const float*)d_in[8];
  const float* gamma = (const float*)d_in[9];
  const float* beta  = (const float*)d_in[10];
  float* out = (float*)d_out;

  char* ws = (char*)d_ws;
  unsigned short* Qb = (unsigned short*)(ws);                    // 8 MiB
  unsigned short* Kb = (unsigned short*)(ws + 8 * 1024 * 1024);  // 8 MiB
  unsigned short* Vt = (unsigned short*)(ws + 16 * 1024 * 1024); // 8 MiB
  unsigned short* Wt = (unsigned short*)(ws + 24 * 1024 * 1024); // 1.5 MiB
  unsigned short* Xbv = (unsigned short*)(ws + 26 * 1024 * 1024); // 8 MiB
  float* qmask = (float*)(ws + 34 * 1024 * 1024);
  float* kbias = qmask + 8192;

  // Xb for queries/keys staged in d_out (16 MiB, dead until attn writes it)
  unsigned short* Xbq = (unsigned short*)d_out;
  unsigned short* Xbk = Xbq + 4194304;

  wt_kernel<<<384, 256, 0, stream>>>(Wq, Wk, Wv, Wt);
  xcvt_kernel<<<6144, 256, 0, stream>>>(queries, keys, values, Xbq, Xbk, Xbv,
                                        qmask, kbias);
  proj_kernel<<<dim3(192, 4), 256, 0, stream>>>(Xbq, Xbk, Xbv, bq, bk, bv,
                                                Wt, Qb, Kb, Vt);
  attn_kernel<<<dim3(32, 16), 256, 0, stream>>>(Qb, Kb, Vt, qmask, kbias,
                                                queries, out);
  ln_kernel<<<2048, 256, 0, stream>>>(out, gamma, beta);
}